// Round 8
// baseline (131.608 us; speedup 1.0000x reference)
//
#include <hip/hip_runtime.h>
#include <hip/hip_bf16.h>

#define BB   8
#define SCTX 4096
#define SQ   512
#define EE   300
#define HH   128
#define EP   320    // E padded to multiple of 32
#define CST  328    // k_qlog staged E-row stride (shorts)
#define CSH  168    // k_attn phase-A half-k staging stride (shorts; 336 B = 21x16 B)
#define LOG2E 1.4426950408889634f

// HIP predefines short4/float4/uint4 (hip_vector_types.h) — never shadow them.
typedef short bhalf4 __attribute__((ext_vector_type(4)));
typedef short short8 __attribute__((ext_vector_type(8)));
typedef float f32x4  __attribute__((ext_vector_type(4)));
typedef unsigned u32x4 __attribute__((ext_vector_type(4)));

#define MFMA16(a, b, c) __builtin_amdgcn_mfma_f32_16x16x32_bf16((a), (b), (c), 0, 0, 0)

__device__ __forceinline__ short f2bf(float f) {
  unsigned u = __builtin_bit_cast(unsigned, f);
  u += 0x7fffu + ((u >> 16) & 1u);
  return (short)(u >> 16);
}
__device__ __forceinline__ float bf2f(short s) {
  return __builtin_bit_cast(float, ((unsigned)(unsigned short)s) << 16);
}
__device__ __forceinline__ unsigned pack2(float a, float b) {
  return (unsigned)(unsigned short)f2bf(a) | ((unsigned)(unsigned short)f2bf(b) << 16);
}
// global -> LDS direct DMA, 16 B/lane. LDS dest = wave-uniform base + lane*16 (m104);
// global source is per-lane (swizzle goes on the SOURCE, rule #21).
__device__ __forceinline__ void gload16(const void* g, void* lds) {
  __builtin_amdgcn_global_load_lds(
      (const __attribute__((address_space(1))) void*)g,
      (__attribute__((address_space(3))) void*)lds, 16, 0, 0);
}

// ---------------- kernel 0: W (fp32 [128][300]) -> bf16 fragment-swizzled wsw ---------
__global__ void k_wpad(const float* __restrict__ W, short* __restrict__ wsw) {
  const int h = blockIdx.x, k = threadIdx.x;
  float v = (k < EE) ? W[h * EE + k] : 0.0f;
  const int m = h >> 4, t = h & 15, kk = k >> 5, quad = (k >> 3) & 3, j = k & 7;
  wsw[((kk * 8 + m) * 64 + quad * 16 + t) * 8 + j] = f2bf(v);
}

// ---------------- kernel 1: qst logits = relu(qst @ W^T + b) -> ql [b][q][h], qlT [b][h][q]
__global__ __launch_bounds__(256) void k_qlog(const float* __restrict__ qst,
                                              const short* __restrict__ wsw,
                                              const float* __restrict__ bias,
                                              short* __restrict__ ql,
                                              short* __restrict__ qlT) {
  const int b = blockIdx.y;
  const int m0 = blockIdx.x * 32;
  const int tid = threadIdx.x;
  const int w = tid >> 6, l = tid & 63, t = l & 15, quad = l >> 4;
  const int g = w >> 1, hf = w & 1;

  __shared__ __align__(16) short cst[32 * CST];

  const float4* cbase = (const float4*)(qst + (size_t)(b * SQ + m0) * EE);
#pragma unroll
  for (int j = 0; j < 10; ++j) {
    int i4 = tid + j * 256;
    if (i4 < 2400) {
      float4 v = cbase[i4];
      int row = i4 / 75, c4 = i4 - row * 75;
      bhalf4 s4; s4[0] = f2bf(v.x); s4[1] = f2bf(v.y); s4[2] = f2bf(v.z); s4[3] = f2bf(v.w);
      *(bhalf4*)(cst + row * CST + c4 * 4) = s4;
    }
  }
  for (int i = tid; i < 320; i += 256) {
    int row = i / 10, c = (i - row * 10) * 2;
    *(int*)&cst[row * CST + 300 + c] = 0;
  }
  __syncthreads();

  const short* arow = cst + (g * 16 + t) * CST;
  f32x4 acc[4] = {};
#pragma unroll
  for (int kk = 0; kk < 10; ++kk) {
    const int k = kk * 32 + quad * 8;
    short8 a = *(const short8*)(arow + k);
    short8 w8[4];
#pragma unroll
    for (int n = 0; n < 4; ++n)
      w8[n] = *(const short8*)(wsw + ((kk * 8 + hf * 4 + n) * 64 + l) * 8);
#pragma unroll
    for (int n = 0; n < 4; ++n) acc[n] = MFMA16(a, w8[n], acc[n]);
  }
#pragma unroll
  for (int n = 0; n < 4; ++n) {
    const int h = (hf * 4 + n) * 16 + t;
    const float bv = bias[h];
    bhalf4 s4;
#pragma unroll
    for (int r = 0; r < 4; ++r) {
      float v = fmaxf(acc[n][r] + bv, 0.0f);
      short s16 = f2bf(v);
      s4[r] = s16;
      const int row = m0 + g * 16 + quad * 4 + r;
      ql[((size_t)b * SQ + row) * HH + h] = s16;
    }
    *(bhalf4*)&qlT[((size_t)b * HH + h) * SQ + m0 + g * 16 + quad * 4] = s4;
  }
}

// ---------------- kernel 2: fused ctx-logits + QK^T + softmax (no-max) + PV ------------
// R18 OCCUPANCY RESTRUCTURE. grid (SCTX/32, B) = 1024 blocks; block 256 thr = 4 waves;
// wave w: rg=w&1 (ctx rows m0+rg*16..+15), qh=w>>1 (q-half of each 64-q chunk).
// LEDGER: R11 global-B = latency collapse. R14 tr_b16 = wrong elem order. R15 reg
//   double-buffer = scratch spills. R12/R16/R17: staging variants + ILP batching all
//   ~40us -> compiler already interleaves within barriers; the invariant was 2 blocks/CU
//   lockstep. R18 attacks TLP: LDS 65.5->33 KB => 4 blocks/CU (16 waves/CU).
//  * chunks of 64 q (8 chunks): qch [64 q][128 h] 16KB + vch [128 h][64 q] 16KB,
//    XOR-swizzled (byte ^ (row&7)<<4), DMA-staged (R16 scheme), V one-phase early.
//  * phase A produces af IN REGISTERS: acc=MFMA16(w8,a) gives lane(t,quad) r =
//    CL[ctx=t][h=n*16+quad*4+r]; bias+relu+pack2+32 shuffles -> af (mirror of the
//    verified X-phase transform). clt LDS round-trip deleted. Phase-A W-GEMM is
//    duplicated across the 2 q-half waves (80 MFMA/wave) - MFMA pipe is 7% busy.
//  * epilogue: q-half partial o/rsum combined via LDS (qch area, conflict-free
//    n*1024B + lane*16B layout), then waves qh=0 normalize and store.
// Max-subtraction dropped (S_max ~16 << 88; -8 centering in maskh; R10-verified).
// __launch_bounds__ stays (256,2): min-waves 3+ historically forces spill binaries
// (R6/R8); we aim for <=128 VGPR organically -> 4 blocks/CU (LDS allows 4.7).
__global__ __launch_bounds__(256, 2) void k_attn(const float* __restrict__ ctx,
                                                 const short* __restrict__ wsw,
                                                 const float* __restrict__ bias,
                                                 const int* __restrict__ mask,
                                                 const short* __restrict__ ql,
                                                 const short* __restrict__ qlT,
                                                 float* __restrict__ out) {
  const int b = blockIdx.y;
  const int m0 = blockIdx.x * 32;
  const int tid = threadIdx.x;
  const int w = tid >> 6, l = tid & 63, t = l & 15, quad = l >> 4;
  const int rg = w & 1, qh = w >> 1;

  __shared__ __align__(16) short uq[8192];   // qch [64][128] (16 KB); epilogue o-xfer
  __shared__ __align__(16) short uv[8192];   // csth [32][CSH] (10.5 KB) -> vch [128][64]
  __shared__ __align__(16) short maskh[SQ];  // bf16 mask (1 KB); epilogue rtot-xfer
  short* qch = uq;
  short* csth = uv;
  short* vch = uv;

  const int rl4 = l >> 4;          // DMA row-within-call (qch)
  const int cbq = (l & 15) * 16;   // DMA linear col-byte in 256-B q-row
  const int rl8 = l >> 3;          // DMA row-within-call (vch)
  const int cbv = (l & 7) * 16;    // DMA linear col-byte in 128-B h-row

  auto stageQ = [&](int c) {
#pragma unroll
    for (int s = 0; s < 4; ++s) {
      const int row = w * 16 + s * 4 + rl4;
      gload16((const char*)(ql + ((size_t)b * SQ + c * 64 + row) * HH) +
                  (cbq ^ ((row & 7) << 4)),
              qch + (w * 16 + s * 4) * 128);
    }
  };
  auto stageV = [&](int c) {
#pragma unroll
    for (int s = 0; s < 4; ++s) {
      const int row = w * 32 + s * 8 + rl8;
      gload16((const char*)(qlT + ((size_t)b * HH + row) * SQ + c * 64) +
                  (cbv ^ ((row & 7) << 4)),
              vch + (w * 32 + s * 8) * 64);
    }
  };

  stageQ(0);  // qch untouched by phase A; flies under all of it

  for (int i = tid; i < SQ; i += 256)
    maskh[i] = f2bf(mask[b * SQ + i] ? -8.0f : -1e30f);  // -8 = exp-centering offset

  // ---- phase A: ctx_logits [32 rows][128 h], k split in two halves through csth ----
  f32x4 acc[8] = {};
  for (int kh = 0; kh < 2; ++kh) {
    if (kh == 0) {
#pragma unroll
      for (int j = 0; j < 5; ++j) {           // 1280 float4 = 32 rows x 40
        int i4 = tid + j * 256;
        int row = i4 / 40, c4 = i4 - row * 40;
        float4 v = *(const float4*)(ctx + ((size_t)b * SCTX + m0 + row) * EE + c4 * 4);
        bhalf4 s4; s4[0] = f2bf(v.x); s4[1] = f2bf(v.y); s4[2] = f2bf(v.z); s4[3] = f2bf(v.w);
        *(bhalf4*)(csth + row * CSH + c4 * 4) = s4;
      }
    } else {
#pragma unroll
      for (int j = 0; j < 5; ++j) {           // 1120 float4 = 32 rows x 35
        int i4 = tid + j * 256;
        if (i4 < 1120) {
          int row = i4 / 35, c4 = i4 - row * 35;
          float4 v = *(const float4*)(ctx + ((size_t)b * SCTX + m0 + row) * EE + 160 + c4 * 4);
          bhalf4 s4; s4[0] = f2bf(v.x); s4[1] = f2bf(v.y); s4[2] = f2bf(v.z); s4[3] = f2bf(v.w);
          *(bhalf4*)(csth + row * CSH + c4 * 4) = s4;
        }
      }
      for (int i = tid; i < 320; i += 256) {  // zero k=300..319 (local 140..159)
        int row = i / 10, ci = (i - row * 10) * 2;
        *(int*)&csth[row * CSH + 140 + ci] = 0;
      }
    }
    __syncthreads();
    const short* arow = csth + (rg * 16 + t) * CSH;
#pragma unroll
    for (int kkl = 0; kkl < 5; ++kkl) {
      const int kk = kh * 5 + kkl;
      short8 a = *(const short8*)(arow + kkl * 32 + quad * 8);
#pragma unroll
      for (int n = 0; n < 8; ++n) {
        short8 w8 = *(const short8*)(wsw + ((kk * 8 + n) * 64 + l) * 8);
        acc[n] = MFMA16(w8, a, acc[n]);  // D: lane(t,quad) r = CL[ctx=t][h=n*16+quad*4+r]
      }
    }
    __syncthreads();  // csth reads drained before restage / V(0) overwrite
  }

  // bias + relu + pack + shuffle -> af in registers (mirror of X-phase transform)
  const int srcA = ((quad & 1) * 2) * 16 + t;
  const int srcB = srcA + 16;
  const bool hiq = quad >= 2;
  unsigned pkA[8][2];
#pragma unroll
  for (int n = 0; n < 8; ++n) {
    float4 bv = *(const float4*)(bias + n * 16 + quad * 4);
    pkA[n][0] = pack2(fmaxf(acc[n][0] + bv.x, 0.f), fmaxf(acc[n][1] + bv.y, 0.f));
    pkA[n][1] = pack2(fmaxf(acc[n][2] + bv.z, 0.f), fmaxf(acc[n][3] + bv.w, 0.f));
  }
  short8 af[4];
#pragma unroll
  for (int kk = 0; kk < 4; ++kk) {
    unsigned e0 = (unsigned)__shfl((int)pkA[kk * 2][0], srcA);
    unsigned e1 = (unsigned)__shfl((int)pkA[kk * 2][1], srcA);
    unsigned e2 = (unsigned)__shfl((int)pkA[kk * 2][0], srcB);
    unsigned e3 = (unsigned)__shfl((int)pkA[kk * 2][1], srcB);
    unsigned o0 = (unsigned)__shfl((int)pkA[kk * 2 + 1][0], srcA);
    unsigned o1 = (unsigned)__shfl((int)pkA[kk * 2 + 1][1], srcA);
    unsigned o2 = (unsigned)__shfl((int)pkA[kk * 2 + 1][0], srcB);
    unsigned o3 = (unsigned)__shfl((int)pkA[kk * 2 + 1][1], srcB);
    u32x4 a4;
    a4[0] = hiq ? o0 : e0;
    a4[1] = hiq ? o1 : e1;
    a4[2] = hiq ? o2 : e2;
    a4[3] = hiq ? o3 : e3;
    af[kk] = __builtin_bit_cast(short8, a4);  // af[kk]: CL[ctx=t][h=kk*32+quad*8..+7]
  }

  // ---- chunk loop: 8 x 64-q, single-buffered, V one-phase-early, Q next-chunk-early --
  const int sx = (t & 7) << 3;  // read-side XOR (shorts)
  f32x4 o[8] = {};
  float rtot = 0.0f;
  for (int c = 0; c < 8; ++c) {
    __syncthreads();            // syncA: Q(c) DMA drained; prior vch readers drained
    stageV(c);                  // hides under S/E/X
    // S: wave's 16 ctx x 32 q (q-half qh), operand-swapped
    f32x4 sv[2] = {};
#pragma unroll
    for (int n2 = 0; n2 < 2; ++n2) {
      const short* qr = qch + (qh * 32 + n2 * 16 + t) * 128;
#pragma unroll
      for (int kx = 0; kx < 4; ++kx) {
        short8 b8 = *(const short8*)(qr + ((kx * 32 + quad * 8) ^ sx));
        sv[n2] = MFMA16(b8, af[kx], sv[n2]);
      }
    }
    // E: mask + exp + pack; lane(t,quad) r = P[q=qh*32+n2*16+quad*4+r][ctx=t]
    unsigned pk[4];
#pragma unroll
    for (int n2 = 0; n2 < 2; ++n2) {
      bhalf4 mb = *(const bhalf4*)&maskh[c * 64 + qh * 32 + n2 * 16 + quad * 4];
      float p0 = exp2f((sv[n2][0] + bf2f(mb[0])) * LOG2E);
      float p1 = exp2f((sv[n2][1] + bf2f(mb[1])) * LOG2E);
      float p2 = exp2f((sv[n2][2] + bf2f(mb[2])) * LOG2E);
      float p3 = exp2f((sv[n2][3] + bf2f(mb[3])) * LOG2E);
      rtot += (p0 + p1) + (p2 + p3);
      pk[n2 * 2 + 0] = pack2(p0, p1);
      pk[n2 * 2 + 1] = pack2(p2, p3);
    }
    // X: shuffle P into PV A-fragment
    unsigned sA[4], sB[4];
#pragma unroll
    for (int i = 0; i < 4; ++i) {
      sA[i] = (unsigned)__shfl((int)pk[i], srcA);
      sB[i] = (unsigned)__shfl((int)pk[i], srcB);
    }
    __syncthreads();            // syncB: V(c) DMA drained; S qch reads drained
    if (c < 7) stageQ(c + 1);   // hides under PV + next syncA
    u32x4 av;
    av[0] = hiq ? sA[2] : sA[0];
    av[1] = hiq ? sA[3] : sA[1];
    av[2] = hiq ? sB[2] : sB[0];
    av[3] = hiq ? sB[3] : sB[1];
    short8 pa = __builtin_bit_cast(short8, av);
#pragma unroll
    for (int n = 0; n < 8; ++n) {
      short8 v8 = *(const short8*)&vch[(n * 16 + t) * 64 + ((qh * 32 + quad * 8) ^ sx)];
      o[n] = MFMA16(pa, v8, o[n]);  // o[n] lane(t,quad) r = O[ctx=quad*4+r][h=n*16+t]
    }
  }

  // ---- epilogue: combine q-halves via LDS (qch + maskh areas are dead) ----
  float* obuf = (float*)uq;       // 4096 floats: 2 regions x 2048
  float* rbuf = (float*)maskh;    // 256 floats: 2 regions x 64
  if (qh == 1) {
#pragma unroll
    for (int n = 0; n < 8; ++n)
      *(f32x4*)&obuf[rg * 2048 + n * 256 + l * 4] = o[n];
    rbuf[rg * 64 + l] = rtot;
  }
  __syncthreads();
  if (qh == 0) {
    rtot += rbuf[rg * 64 + l];
#pragma unroll
    for (int n = 0; n < 8; ++n)
      o[n] += *(const f32x4*)&obuf[rg * 2048 + n * 256 + l * 4];
    rtot += __shfl_xor(rtot, 16);
    rtot += __shfl_xor(rtot, 32);  // lane x holds full denom for ctx row (x&15)
    f32x4 rinv;
#pragma unroll
    for (int r = 0; r < 4; ++r) rinv[r] = 1.0f / __shfl(rtot, quad * 4 + r);
    float* obase = out + ((size_t)b * SCTX + m0 + rg * 16) * HH;
#pragma unroll
    for (int n = 0; n < 8; ++n)
#pragma unroll
      for (int r = 0; r < 4; ++r)
        obase[(quad * 4 + r) * HH + n * 16 + t] = o[n][r] * rinv[r];
  }
}

extern "C" void kernel_launch(void* const* d_in, const int* in_sizes, int n_in,
                              void* d_out, int out_size, void* d_ws, size_t ws_size,
                              hipStream_t stream) {
  const float* ctx  = (const float*)d_in[0];
  const float* qst  = (const float*)d_in[1];
  const int*   mask = (const int*)d_in[2];
  const float* W    = (const float*)d_in[3];
  const float* bias = (const float*)d_in[4];
  float* out = (float*)d_out;

  // ws: wsw 80 KiB | ql 1 MiB | qlT 1 MiB
  short* wsw  = (short*)d_ws;
  short* ql   = (short*)((char*)d_ws + 81920);
  short* qlT  = ql + (size_t)BB * SQ * HH;

  k_wpad<<<dim3(HH), dim3(EP), 0, stream>>>(W, wsw);
  k_qlog<<<dim3(SQ / 32, BB), dim3(256), 0, stream>>>(qst, wsw, bias, ql, qlT);
  k_attn<<<dim3(SCTX / 32, BB), dim3(256), 0, stream>>>(ctx, wsw, bias, mask, ql, qlT, out);
}

// Round 9
// 121.171 us; speedup vs baseline: 1.0861x; 1.0861x over previous
//
#include <hip/hip_runtime.h>
#include <hip/hip_bf16.h>

#define BB   8
#define SCTX 4096
#define SQ   512
#define EE   300
#define HH   128
#define EP   320    // E padded to multiple of 32
#define CST  328    // staged fp32->bf16 E-row stride (shorts)
#define LOG2E 1.4426950408889634f

// HIP predefines short4/float4/uint4 (hip_vector_types.h) — never shadow them.
typedef short bhalf4 __attribute__((ext_vector_type(4)));
typedef short short8 __attribute__((ext_vector_type(8)));
typedef float f32x4  __attribute__((ext_vector_type(4)));
typedef unsigned u32x4 __attribute__((ext_vector_type(4)));

#define MFMA16(a, b, c) __builtin_amdgcn_mfma_f32_16x16x32_bf16((a), (b), (c), 0, 0, 0)
#define SBAR()   __builtin_amdgcn_s_barrier()
#define SCHED0() __builtin_amdgcn_sched_barrier(0)

__device__ __forceinline__ short f2bf(float f) {
  unsigned u = __builtin_bit_cast(unsigned, f);
  u += 0x7fffu + ((u >> 16) & 1u);
  return (short)(u >> 16);
}
__device__ __forceinline__ float bf2f(short s) {
  return __builtin_bit_cast(float, ((unsigned)(unsigned short)s) << 16);
}
__device__ __forceinline__ unsigned pack2(float a, float b) {
  return (unsigned)(unsigned short)f2bf(a) | ((unsigned)(unsigned short)f2bf(b) << 16);
}
// global -> LDS direct DMA, 16 B/lane. LDS dest = wave-uniform base + lane*16 (m104);
// global source is per-lane (swizzle goes on the SOURCE, rule #21).
__device__ __forceinline__ void gload16(const void* g, void* lds) {
  __builtin_amdgcn_global_load_lds(
      (const __attribute__((address_space(1))) void*)g,
      (__attribute__((address_space(3))) void*)lds, 16, 0, 0);
}

// ---------------- kernel 0: W (fp32 [128][300]) -> bf16 fragment-swizzled wsw ---------
__global__ void k_wpad(const float* __restrict__ W, short* __restrict__ wsw) {
  const int h = blockIdx.x, k = threadIdx.x;
  float v = (k < EE) ? W[h * EE + k] : 0.0f;
  const int m = h >> 4, t = h & 15, kk = k >> 5, quad = (k >> 3) & 3, j = k & 7;
  wsw[((kk * 8 + m) * 64 + quad * 16 + t) * 8 + j] = f2bf(v);
}

// ---------------- kernel 1: qst logits = relu(qst @ W^T + b) -> ql [b][q][h], qlT [b][h][q]
__global__ __launch_bounds__(256) void k_qlog(const float* __restrict__ qst,
                                              const short* __restrict__ wsw,
                                              const float* __restrict__ bias,
                                              short* __restrict__ ql,
                                              short* __restrict__ qlT) {
  const int b = blockIdx.y;
  const int m0 = blockIdx.x * 32;
  const int tid = threadIdx.x;
  const int w = tid >> 6, l = tid & 63, t = l & 15, quad = l >> 4;
  const int g = w >> 1, hf = w & 1;

  __shared__ __align__(16) short cst[32 * CST];

  const float4* cbase = (const float4*)(qst + (size_t)(b * SQ + m0) * EE);
#pragma unroll
  for (int j = 0; j < 10; ++j) {
    int i4 = tid + j * 256;
    if (i4 < 2400) {
      float4 v = cbase[i4];
      int row = i4 / 75, c4 = i4 - row * 75;
      bhalf4 s4; s4[0] = f2bf(v.x); s4[1] = f2bf(v.y); s4[2] = f2bf(v.z); s4[3] = f2bf(v.w);
      *(bhalf4*)(cst + row * CST + c4 * 4) = s4;
    }
  }
  for (int i = tid; i < 320; i += 256) {
    int row = i / 10, c = (i - row * 10) * 2;
    *(int*)&cst[row * CST + 300 + c] = 0;
  }
  __syncthreads();

  const short* arow = cst + (g * 16 + t) * CST;
  f32x4 acc[4] = {};
#pragma unroll
  for (int kk = 0; kk < 10; ++kk) {
    const int k = kk * 32 + quad * 8;
    short8 a = *(const short8*)(arow + k);
    short8 w8[4];
#pragma unroll
    for (int n = 0; n < 4; ++n)
      w8[n] = *(const short8*)(wsw + ((kk * 8 + hf * 4 + n) * 64 + l) * 8);
#pragma unroll
    for (int n = 0; n < 4; ++n) acc[n] = MFMA16(a, w8[n], acc[n]);
  }
#pragma unroll
  for (int n = 0; n < 4; ++n) {
    const int h = (hf * 4 + n) * 16 + t;
    const float bv = bias[h];
    bhalf4 s4;
#pragma unroll
    for (int r = 0; r < 4; ++r) {
      float v = fmaxf(acc[n][r] + bv, 0.0f);
      short s16 = f2bf(v);
      s4[r] = s16;
      const int row = m0 + g * 16 + quad * 4 + r;
      ql[((size_t)b * SQ + row) * HH + h] = s16;
    }
    *(bhalf4*)&qlT[((size_t)b * HH + h) * SQ + m0 + g * 16 + quad * 4] = s4;
  }
}

// ---------------- kernel 2: fused ctx-logits + QK^T + softmax (no-max) + PV ------------
// grid (SCTX/64, B) = 512 blocks; 4 waves; wave w owns ctx rows m0+w*16..+15, full q.
//
// LEDGER: R11 global-B = latency collapse. R14 tr_b16 = wrong elem order. R15 reg dbuf =
//   scratch spills. R12/R16/R17 staging variants + ILP batching all ~40us. R18 occupancy
//   2x (37%) REGRESSED to 56us -> TLP not binding; barrier frequency is. Invariant cost:
//   every __syncthreads drains vmcnt(0) of DMA issued ~1 phase earlier.
// R19 (this): T3/T4 counted-vmcnt double-buffered chunk pipeline.
//   8 chunks x 64 q; qbuf/vbuf x2 (64 KB; 2 blocks/CU unchanged). Steady state:
//   [barrier1: vmcnt(8) (chunk c done; c+1's 8 calls STAY IN FLIGHT) -> S/E/X/PV on
//    buf[c&1] -> lgkmcnt(0); barrier2 -> stage(c+2) into buf[c&1]]
//   Hazards: b1 publishes c (all waves counted-waited own calls); stage(c+1)'s target
//   buffer's readers (chunk c-1) drained at b2(c-1) BEFORE issuance -> WAR safe.
//   b2: every wave's reads of buf[c&1] lgkm-drained before c+2 DMA can land.
//   No other vmem ops in loop -> per-wave vmcnt counts are exact. sched_barrier(0)
//   fences around all asm waits/barriers (rule #18).
// Max-subtraction dropped (S_max ~16 << 88; -8 centering in maskh; R10-verified).
// __launch_bounds__ min-waves MUST stay 2 (3 => spill binary, R6/R8).
__global__ __launch_bounds__(256, 2) void k_attn(const float* __restrict__ ctx,
                                                 const short* __restrict__ wsw,
                                                 const float* __restrict__ bias,
                                                 const int* __restrict__ mask,
                                                 const short* __restrict__ ql,
                                                 const short* __restrict__ qlT,
                                                 float* __restrict__ out) {
  const int b = blockIdx.y;
  const int m0 = blockIdx.x * 64;
  const int tid = threadIdx.x;
  const int w = tid >> 6, l = tid & 63, t = l & 15, quad = l >> 4;
  const int g = w >> 1, hf = w & 1;

  __shared__ __align__(16) short uq[16384];  // cst [32][328] (10,496 sh) | qbuf0,qbuf1 [64][128]
  __shared__ __align__(16) short uv[16384];  // clt [64][136] (8,704 sh)  | vbuf0,vbuf1 [128][64]
  __shared__ __align__(16) short maskh[SQ];  // bf16 mask+exp-centering offsets
  short* cst = uq;
  short* clt = uv;
  short* qb0 = uq;          short* qb1 = uq + 8192;
  short* vb0 = uv;          short* vb1 = uv + 8192;

  for (int i = tid; i < SQ; i += 256)
    maskh[i] = f2bf(mask[b * SQ + i] ? -8.0f : -1e30f);  // -8 = exp-centering offset

  // ---- phase A: ctx_logits tile [64][128], two 32-row halves (R16/R17-proven) ----
  for (int i = 0; i < 2; ++i) {
    const float4* cbase = (const float4*)(ctx + ((size_t)b * SCTX + m0 + i * 32) * EE);
#pragma unroll
    for (int j = 0; j < 10; ++j) {
      int i4 = tid + j * 256;
      if (i4 < 2400) {
        float4 v = cbase[i4];
        int row = i4 / 75, c4 = i4 - row * 75;
        bhalf4 s4; s4[0] = f2bf(v.x); s4[1] = f2bf(v.y); s4[2] = f2bf(v.z); s4[3] = f2bf(v.w);
        *(bhalf4*)(cst + row * CST + c4 * 4) = s4;
      }
    }
    for (int k = tid; k < 320; k += 256) {
      int row = k / 10, c = (k - row * 10) * 2;
      *(int*)&cst[row * CST + 300 + c] = 0;
    }
    __syncthreads();
    const short* arow = cst + (g * 16 + t) * CST;
    f32x4 acc[4] = {};
#pragma unroll
    for (int kk = 0; kk < 10; ++kk) {
      const int k = kk * 32 + quad * 8;
      short8 a = *(const short8*)(arow + k);
      short8 w8[4];
#pragma unroll
      for (int n = 0; n < 4; ++n)
        w8[n] = *(const short8*)(wsw + ((kk * 8 + hf * 4 + n) * 64 + l) * 8);
#pragma unroll
      for (int n = 0; n < 4; ++n) acc[n] = MFMA16(a, w8[n], acc[n]);
    }
#pragma unroll
    for (int n = 0; n < 4; ++n) {
      const int h = (hf * 4 + n) * 16 + t;
      const float bv = bias[h];
#pragma unroll
      for (int r = 0; r < 4; ++r) {
        float v = fmaxf(acc[n][r] + bv, 0.0f);
        clt[(i * 32 + g * 16 + quad * 4 + r) * 136 + h] = f2bf(v);
      }
    }
    __syncthreads();  // clt written; cst free
  }

  // A-fragments for this wave's 16 ctx rows
  short8 af[4];
#pragma unroll
  for (int kk = 0; kk < 4; ++kk)
    af[kk] = *(const short8*)&clt[(w * 16 + t) * 136 + kk * 32 + quad * 8];
  __syncthreads();  // ALL waves' af (clt) reads drained before DMA overwrites uq/uv

  // ---- chunk machinery ----
  const int srcA = ((quad & 1) * 2) * 16 + t;  // shfl source lanes for P-assembly
  const int srcB = srcA + 16;
  const bool hiq = quad >= 2;
  const int sx  = (t & 7) << 3;   // read-side XOR (shorts)
  const int rl4 = l >> 4;         // DMA row-within-call (qbuf)
  const int cbq = (l & 15) * 16;  // DMA linear col-byte in 256-B q-row
  const int rl8 = l >> 3;         // DMA row-within-call (vbuf)
  const int cbv = (l & 7) * 16;   // DMA linear col-byte in 128-B h-row

  // 8 gload16/wave/chunk: Q 4 calls (4 rows each) + V 4 calls (8 rows each).
  auto stageTo = [&](short* qb, short* vb, int c) {
#pragma unroll
    for (int s = 0; s < 4; ++s) {
      const int row = w * 16 + s * 4 + rl4;
      gload16((const char*)(ql + ((size_t)b * SQ + c * 64 + row) * HH) +
                  (cbq ^ ((row & 7) << 4)),
              qb + (w * 16 + s * 4) * 128);
    }
#pragma unroll
    for (int s = 0; s < 4; ++s) {
      const int row = w * 32 + s * 8 + rl8;
      gload16((const char*)(qlT + ((size_t)b * HH + row) * SQ + c * 64) +
                  (cbv ^ ((row & 7) << 4)),
              vb + (w * 32 + s * 8) * 64);
    }
  };

  stageTo(qb0, vb0, 0);  // 8 calls
  stageTo(qb1, vb1, 1);  // 8 calls  (16 in flight)

  f32x4 o[8] = {};
  float rtot = 0.0f;
  for (int c = 0; c < 8; ++c) {
    short* qch = (c & 1) ? qb1 : qb0;
    short* vch = (c & 1) ? vb1 : vb0;
    // barrier1: counted wait — chunk c's 8 calls are the oldest; c+1's stay in flight.
    if (c < 7) { asm volatile("s_waitcnt vmcnt(8)" ::: "memory"); }
    else       { asm volatile("s_waitcnt vmcnt(0)" ::: "memory"); }
    SCHED0(); SBAR(); SCHED0();

    // ---- S: 16 MFMA, 4 indep chains (operand-swapped) ----
    f32x4 sv[4] = {};
#pragma unroll
    for (int n2 = 0; n2 < 4; ++n2) {
      const short* qr = qch + (n2 * 16 + t) * 128;
#pragma unroll
      for (int kx = 0; kx < 4; ++kx) {
        short8 b8 = *(const short8*)(qr + ((kx * 32 + quad * 8) ^ sx));
        sv[n2] = MFMA16(b8, af[kx], sv[n2]);
      }
    }
    // ---- E: mask + exp + pack; lane(t,quad) r = P[q=c*64+n2*16+quad*4+r][ctx=t] ----
    unsigned pk[8];
#pragma unroll
    for (int n2 = 0; n2 < 4; ++n2) {
      bhalf4 mb = *(const bhalf4*)&maskh[c * 64 + n2 * 16 + quad * 4];
      float p0 = exp2f((sv[n2][0] + bf2f(mb[0])) * LOG2E);
      float p1 = exp2f((sv[n2][1] + bf2f(mb[1])) * LOG2E);
      float p2 = exp2f((sv[n2][2] + bf2f(mb[2])) * LOG2E);
      float p3 = exp2f((sv[n2][3] + bf2f(mb[3])) * LOG2E);
      rtot += (p0 + p1) + (p2 + p3);
      pk[n2 * 2 + 0] = pack2(p0, p1);
      pk[n2 * 2 + 1] = pack2(p2, p3);
    }
    // ---- X: 16 shuffles ----
    unsigned sA[8], sB[8];
#pragma unroll
    for (int i = 0; i < 8; ++i) {
      sA[i] = (unsigned)__shfl((int)pk[i], srcA);
      sB[i] = (unsigned)__shfl((int)pk[i], srcB);
    }
    // ---- PV: 16 MFMA over 2 q-subblocks ----
#pragma unroll
    for (int kk2 = 0; kk2 < 2; ++kk2) {
      u32x4 av;
      av[0] = hiq ? sA[kk2 * 4 + 2] : sA[kk2 * 4 + 0];
      av[1] = hiq ? sA[kk2 * 4 + 3] : sA[kk2 * 4 + 1];
      av[2] = hiq ? sB[kk2 * 4 + 2] : sB[kk2 * 4 + 0];
      av[3] = hiq ? sB[kk2 * 4 + 3] : sB[kk2 * 4 + 1];
      short8 pa = __builtin_bit_cast(short8, av);
      const int co = (kk2 * 32 + quad * 8) ^ sx;
#pragma unroll
      for (int n = 0; n < 8; ++n) {
        short8 v8 = *(const short8*)&vch[(n * 16 + t) * 64 + co];
        o[n] = MFMA16(pa, v8, o[n]);
      }
    }
    // barrier2 (lgkm-only): all reads of buf[c&1] drained; then restage it with c+2.
    if (c < 7) {
      asm volatile("s_waitcnt lgkmcnt(0)" ::: "memory");
      SCHED0(); SBAR(); SCHED0();
      if (c < 6) stageTo(qch, vch, c + 2);
    }
  }

  // ---- epilogue (register/shuffle only; no LDS) ----
  rtot += __shfl_xor(rtot, 16);
  rtot += __shfl_xor(rtot, 32);  // lane x holds full denom for ctx row (x&15)
  f32x4 rinv;
#pragma unroll
  for (int r = 0; r < 4; ++r) rinv[r] = 1.0f / __shfl(rtot, quad * 4 + r);
  float* obase = out + ((size_t)b * SCTX + m0 + w * 16) * HH;
#pragma unroll
  for (int n = 0; n < 8; ++n)
#pragma unroll
    for (int r = 0; r < 4; ++r)
      obase[(quad * 4 + r) * HH + n * 16 + t] = o[n][r] * rinv[r];
}

extern "C" void kernel_launch(void* const* d_in, const int* in_sizes, int n_in,
                              void* d_out, int out_size, void* d_ws, size_t ws_size,
                              hipStream_t stream) {
  const float* ctx  = (const float*)d_in[0];
  const float* qst  = (const float*)d_in[1];
  const int*   mask = (const int*)d_in[2];
  const float* W    = (const float*)d_in[3];
  const float* bias = (const float*)d_in[4];
  float* out = (float*)d_out;

  // ws: wsw 80 KiB | ql 1 MiB | qlT 1 MiB
  short* wsw  = (short*)d_ws;
  short* ql   = (short*)((char*)d_ws + 81920);
  short* qlT  = ql + (size_t)BB * SQ * HH;

  k_wpad<<<dim3(HH), dim3(EP), 0, stream>>>(W, wsw);
  k_qlog<<<dim3(SQ / 32, BB), dim3(256), 0, stream>>>(qst, wsw, bias, ql, qlT);
  k_attn<<<dim3(SCTX / 64, BB), dim3(256), 0, stream>>>(ctx, wsw, bias, mask, ql, qlT, out);
}